// Round 14
// baseline (1312.525 us; speedup 1.0000x reference)
//
#include <hip/hip_runtime.h>

typedef float f32x4 __attribute__((ext_vector_type(4)));
typedef __bf16 bf16x8 __attribute__((ext_vector_type(8)));
typedef unsigned int u32x4 __attribute__((ext_vector_type(4)));
typedef unsigned short u16;
typedef unsigned int u32;

#define VOCAB 50257
#define KDIM 1024
#define MROWS 2048
#define TSEQ 256
#define NBLK 64
#define NTILE 393            // ceil(VOCAB/128)
#define NT (NTILE * 2)       // partial slots per row (2 waves/col-tile)
#define LOGN ((size_t)MROWS * VOCAB)

__device__ __forceinline__ u16 f2bf(float f) {
    u32 u = __builtin_bit_cast(u32, f);
    u = (u + 0x7FFFu + ((u >> 16) & 1u)) >> 16;
    return (u16)u;
}

__device__ __forceinline__ float sigm(float x) { return 1.0f / (1.0f + __expf(-x)); }

__device__ __forceinline__ u32 min4u(u32x4 v) {
    u32 a = v.x < v.y ? v.x : v.y;
    u32 b = v.z < v.w ? v.z : v.w;
    return a < b ? a : b;
}

__device__ __forceinline__ ushort4 cvt4(float4 v) {
    ushort4 o;
    o.x = f2bf(v.x); o.y = f2bf(v.y); o.z = f2bf(v.z); o.w = f2bf(v.w);
    return o;
}

// ---------------- consolidated prep: one launch (no embW conv here) ----------------
// [0,4096)       conv Wih
// [4096,8192)    conv Whh
// [8192,10240)   gather_emb
// [10240,14352)  init_hseq
// [14352,14368)  bias_sum

#define PB_GATH 8192
#define PB_HSEQ 10240
#define PB_BIAS 14352
#define PREP_BLOCKS 14368

__global__ __launch_bounds__(256)
void prep_all(const float4* __restrict__ Wih, ushort4* __restrict__ Wih_bf,
              const float4* __restrict__ Whh, ushort4* __restrict__ Whh_bf,
              const int* __restrict__ x, const float* __restrict__ embW,
              ushort4* __restrict__ emb_bf, u32* __restrict__ hseq,
              const float* __restrict__ bih, const float* __restrict__ bhh,
              float* __restrict__ bsum)
{
    const int bid = blockIdx.x, tid = threadIdx.x;
    if (bid < 4096) {
        long i = (long)bid * 256 + tid;
        Wih_bf[i] = cvt4(Wih[i]);
    } else if (bid < PB_GATH) {
        long i = (long)(bid - 4096) * 256 + tid;
        Whh_bf[i] = cvt4(Whh[i]);
    } else if (bid < PB_HSEQ) {
        int m = bid - PB_GATH;
        int row = x[m];
        float4 v = ((const float4*)(embW + (size_t)row * KDIM))[tid];
        emb_bf[(size_t)m * 256 + tid] = cvt4(v);
    } else if (bid < PB_BIAS) {
        int i = (bid - PB_HSEQ) * 256 + tid;   // < 257*4096
        hseq[i] = (i < 4096) ? 0x00010001u : 0u;
    } else {
        int i = (bid - PB_BIAS) * 256 + tid;
        if (i < 4096) bsum[i] = bih[i] + bhh[i];
    }
}

// ---------------- bf16 MFMA GEMM (C = A * B^T + bias) + embW-conv helpers ----------------
// grid (16, 48): blockIdx.y < 32 -> xproj GEMM (512 blocks, XCD-swizzled over 512);
// blockIdx.y >= 32 -> 256 helper blocks grid-stride converting embW f32->bf16.

#define BM 128
#define BN 128
#define BK 64
#define GBY 32              // gemm blocks in y
#define HBY 16              // helper rows in y (16*16 = 256 helper blocks)

__device__ __forceinline__ void gl_lds16(const u16* g, const u16* l) {
    __builtin_amdgcn_global_load_lds(
        (const __attribute__((address_space(1))) u32*)g,
        (__attribute__((address_space(3))) u32*)l, 16, 0, 0);
}

__global__ __launch_bounds__(256, 2)
void gemm_bt_conv(const u16* __restrict__ A, const u16* __restrict__ Bm,
                  const float* __restrict__ bias, float* __restrict__ C,
                  int N, int Nb, int K, int ldc,
                  const float4* __restrict__ embW, ushort4* __restrict__ embW_bf)
{
    const int tid  = threadIdx.x;

    if (blockIdx.y >= GBY) {                   // ---- helper: embW conversion ----
        long hb = (long)(blockIdx.y - GBY) * gridDim.x + blockIdx.x;   // 0..255
        long i = hb * 256 + tid;
        const long n4 = (long)VOCAB * KDIM / 4;
        const long stride = (long)HBY * gridDim.x * 256;
        for (; i < n4; i += stride) embW_bf[i] = cvt4(embW[i]);
        return;
    }

    __shared__ __align__(16) u16 As[BM * BK];
    __shared__ __align__(16) u16 Bs[BN * BK];
    const int lane = tid & 63;
    const int wid  = tid >> 6;

    const int gx  = gridDim.x;
    const int nwg = gx * GBY;
    const int lin = blockIdx.y * gx + blockIdx.x;
    const int qq = nwg >> 3, rr = nwg & 7;
    const int xcd = lin & 7, idx = lin >> 3;
    const int neu = (xcd < rr) ? (xcd * (qq + 1) + idx)
                               : (rr * (qq + 1) + (xcd - rr) * qq + idx);
    const int bm = neu % gx;
    const int bn = neu / gx;

    const int wr = wid >> 1, wc = wid & 1;

    const u16* gA[4]; const u16* gB[4];
    const u16* ldsA[4]; const u16* ldsB[4];
#pragma unroll
    for (int r = 0; r < 4; ++r) {
        int L = r * 256 + tid;
        int row = L >> 3, ps = L & 7;
        int ls = ps ^ (row & 7);
        gA[r] = A + (size_t)(bm * BM + row) * K + ls * 8;
        int brow = bn * BN + row; brow = brow < Nb ? brow : Nb - 1;
        gB[r] = Bm + (size_t)brow * K + ls * 8;
        ldsA[r] = As + (r * 256 + wid * 64) * 8;
        ldsB[r] = Bs + (r * 256 + wid * 64) * 8;
    }

    const int lrow = lane & 15, ksl = lane >> 4;
    int aoff[4][2], boff[4][2];
#pragma unroll
    for (int i = 0; i < 4; ++i)
#pragma unroll
        for (int ks = 0; ks < 2; ++ks) {
            int ar = wr * 64 + i * 16 + lrow;
            aoff[i][ks] = ar * BK + (((ks * 4 + ksl) ^ (ar & 7)) * 8);
            int br = wc * 64 + i * 16 + lrow;
            boff[i][ks] = br * BK + (((ks * 4 + ksl) ^ (br & 7)) * 8);
        }

    f32x4 acc[4][4] = {};
    for (int kt = 0; kt < K; kt += BK) {
#pragma unroll
        for (int r = 0; r < 4; ++r) gl_lds16(gA[r] + kt, ldsA[r]);
#pragma unroll
        for (int r = 0; r < 4; ++r) gl_lds16(gB[r] + kt, ldsB[r]);
        __syncthreads();
        bf16x8 af[4][2], bfb[4][2];
#pragma unroll
        for (int i = 0; i < 4; ++i)
#pragma unroll
            for (int ks = 0; ks < 2; ++ks) {
                af[i][ks]  = *(const bf16x8*)(As + aoff[i][ks]);
                bfb[i][ks] = *(const bf16x8*)(Bs + boff[i][ks]);
            }
#pragma unroll
        for (int ks = 0; ks < 2; ++ks)
#pragma unroll
            for (int mi = 0; mi < 4; ++mi)
#pragma unroll
                for (int ni = 0; ni < 4; ++ni)
                    acc[mi][ni] = __builtin_amdgcn_mfma_f32_16x16x32_bf16(
                        af[mi][ks], bfb[ni][ks], acc[mi][ni], 0, 0, 0);
        __syncthreads();
    }

    const int crl = lane >> 4, ccl = lane & 15;
    const int row0 = bm * BM + wr * 64, col0 = bn * BN + wc * 64;
#pragma unroll
    for (int ni = 0; ni < 4; ++ni) {
        int col = col0 + ni * 16 + ccl;
        if (col < N) {
            float bv = bias[col];
#pragma unroll
            for (int mi = 0; mi < 4; ++mi) {
                int row = row0 + mi * 16 + crl * 4;
                float* cp = C + (size_t)row * ldc + col;
#pragma unroll
                for (int r = 0; r < 4; ++r)
                    cp[(size_t)r * ldc] = acc[mi][ni][r] + bv;
            }
        }
    }
}

// ---- decoder GEMM: bf16 C (packed into f32 row slots) + fused max/sumexp ----

__global__ __launch_bounds__(256, 3)
void gemm_dec(const u16* __restrict__ A, const u16* __restrict__ Bm,
              const float* __restrict__ bias, u16* __restrict__ Cb,
              float* __restrict__ pmax, float* __restrict__ psum)
{
    const int N = VOCAB, Nb = VOCAB, K = KDIM;
    __shared__ __align__(16) u16 As[BM * BK];
    __shared__ __align__(16) u16 Bs[BN * BK];
    const int tid  = threadIdx.x;
    const int lane = tid & 63;
    const int wid  = tid >> 6;

    const int gx  = gridDim.x;
    const int nwg = gx * gridDim.y;
    const int lin = blockIdx.y * gx + blockIdx.x;
    const int qq = nwg >> 3, rr = nwg & 7;
    const int xcd = lin & 7, idx = lin >> 3;
    const int neu = (xcd < rr) ? (xcd * (qq + 1) + idx)
                               : (rr * (qq + 1) + (xcd - rr) * qq + idx);
    const int bm = neu % gx;
    const int bn = neu / gx;

    const int wr = wid >> 1, wc = wid & 1;

    const u16* gA[4]; const u16* gB[4];
    const u16* ldsA[4]; const u16* ldsB[4];
#pragma unroll
    for (int r = 0; r < 4; ++r) {
        int L = r * 256 + tid;
        int row = L >> 3, ps = L & 7;
        int ls = ps ^ (row & 7);
        gA[r] = A + (size_t)(bm * BM + row) * K + ls * 8;
        int brow = bn * BN + row; brow = brow < Nb ? brow : Nb - 1;
        gB[r] = Bm + (size_t)brow * K + ls * 8;
        ldsA[r] = As + (r * 256 + wid * 64) * 8;
        ldsB[r] = Bs + (r * 256 + wid * 64) * 8;
    }

    const int lrow = lane & 15, ksl = lane >> 4;
    int aoff[4][2], boff[4][2];
#pragma unroll
    for (int i = 0; i < 4; ++i)
#pragma unroll
        for (int ks = 0; ks < 2; ++ks) {
            int ar = wr * 64 + i * 16 + lrow;
            aoff[i][ks] = ar * BK + (((ks * 4 + ksl) ^ (ar & 7)) * 8);
            int br = wc * 64 + i * 16 + lrow;
            boff[i][ks] = br * BK + (((ks * 4 + ksl) ^ (br & 7)) * 8);
        }

    f32x4 acc[4][4] = {};
    for (int kt = 0; kt < K; kt += BK) {
#pragma unroll
        for (int r = 0; r < 4; ++r) gl_lds16(gA[r] + kt, ldsA[r]);
#pragma unroll
        for (int r = 0; r < 4; ++r) gl_lds16(gB[r] + kt, ldsB[r]);
        __syncthreads();
        bf16x8 af[4][2], bfb[4][2];
#pragma unroll
        for (int i = 0; i < 4; ++i)
#pragma unroll
            for (int ks = 0; ks < 2; ++ks) {
                af[i][ks]  = *(const bf16x8*)(As + aoff[i][ks]);
                bfb[i][ks] = *(const bf16x8*)(Bs + boff[i][ks]);
            }
#pragma unroll
        for (int ks = 0; ks < 2; ++ks)
#pragma unroll
            for (int mi = 0; mi < 4; ++mi)
#pragma unroll
                for (int ni = 0; ni < 4; ++ni)
                    acc[mi][ni] = __builtin_amdgcn_mfma_f32_16x16x32_bf16(
                        af[mi][ks], bfb[ni][ks], acc[mi][ni], 0, 0, 0);
        __syncthreads();
    }

    const int crl = lane >> 4, ccl = lane & 15;
    const int row0 = bm * BM + wr * 64, col0 = bn * BN + wc * 64;
    float bve[4]; bool vld[4];
#pragma unroll
    for (int ni = 0; ni < 4; ++ni) {
        int col = col0 + ni * 16 + ccl;
        vld[ni] = col < N;
        bve[ni] = vld[ni] ? bias[col] : 0.f;
    }
    // bf16 logits packed at the front of each f32 row slot: row stride VOCAB*2 u16
#pragma unroll
    for (int ni = 0; ni < 4; ++ni) {
        if (vld[ni]) {
            int col = col0 + ni * 16 + ccl;
#pragma unroll
            for (int mi = 0; mi < 4; ++mi) {
                int row = row0 + mi * 16 + crl * 4;
                u16* cp = Cb + (size_t)row * (VOCAB * 2) + col;
#pragma unroll
                for (int r = 0; r < 4; ++r)
                    cp[(size_t)r * (VOCAB * 2)] = f2bf(acc[mi][ni][r] + bve[ni]);
            }
        }
    }
    // fused partial log-softmax reduction
#pragma unroll
    for (int mi = 0; mi < 4; ++mi)
#pragma unroll
        for (int r = 0; r < 4; ++r) {
            int row = row0 + mi * 16 + crl * 4 + r;
            float v0 = vld[0] ? acc[mi][0][r] + bve[0] : -3.0e38f;
            float v1 = vld[1] ? acc[mi][1][r] + bve[1] : -3.0e38f;
            float v2 = vld[2] ? acc[mi][2][r] + bve[2] : -3.0e38f;
            float v3 = vld[3] ? acc[mi][3][r] + bve[3] : -3.0e38f;
            float rmax = fmaxf(fmaxf(v0, v1), fmaxf(v2, v3));
#pragma unroll
            for (int m2 = 1; m2 < 16; m2 <<= 1) rmax = fmaxf(rmax, __shfl_xor(rmax, m2));
            float rs = __expf(v0 - rmax) + __expf(v1 - rmax) +
                       __expf(v2 - rmax) + __expf(v3 - rmax);
#pragma unroll
            for (int m2 = 1; m2 < 16; m2 <<= 1) rs += __shfl_xor(rs, m2);
            if (ccl == 0) {
                pmax[(size_t)row * NT + bn * 2 + wc] = rmax;
                psum[(size_t)row * NT + bn * 2 + wc] = rs;
            }
        }
}

// ---------------- persistent LSTM (pure 64-block recurrence) ----------------

__global__ __launch_bounds__(256, 1)
void lstm_persist(const u16* __restrict__ Whh,     // [4096][1024] bf16
                  const float* __restrict__ xproj, // [2048][4096] f32
                  u16* __restrict__ hseq,          // [257][64][8][16] bf16
                  u16* __restrict__ hall,          // [2048][1024] bf16
                  float* __restrict__ outTail)     // h[8][1024], c[8][1024] f32
{
    const int tid = threadIdx.x;
    const int bid = blockIdx.x;

    const int lane = tid & 63;
    const int wq   = tid >> 6;                 // gate quadrant (i,f,g,o)
    const int lrow = lane & 15, ksl = lane >> 4;
    const int colbase = bid * 16;

    // persistent Whh fragments, pinned via volatile asm
    bf16x8 Bf[32];
    {
        const u16* bp = Whh + (size_t)(wq * 1024 + colbase + lrow) * KDIM + ksl * 8;
#pragma unroll
        for (int kk = 0; kk < 32; ++kk)
            asm volatile("global_load_dwordx4 %0, %1, off"
                         : "=v"(Bf[kk]) : "v"(bp + kk * 32));
        asm volatile("s_waitcnt vmcnt(0)" ::: "memory");
        __builtin_amdgcn_sched_barrier(0);
    }

    __shared__ float S[4][8][16];
    __shared__ __align__(16) u16 hstage[2][16384];   // 64 KB, XOR-swizzled

    // zero pad region (rows 8..15 of each j-region), once
    for (int i = tid; i < 2 * 64 * 8; i += 256) {
        int buf = i >> 9, rem = i & 511;
        int j = rem >> 3, rowoff = rem & 7;
        u32x4 z = {0, 0, 0, 0};
        *(u32x4*)(&hstage[buf][j * 256 + 128 + rowoff * 16]) = z;
        *(u32x4*)(&hstage[buf][j * 256 + 128 + rowoff * 16 + 8]) = z;
    }

    const bool upd = tid < 128;
    const int b8 = tid >> 4, c16 = tid & 15;
    float creg = 0.f;
    float xp0 = 0.f, xp1 = 0.f, xp2 = 0.f, xp3 = 0.f;
    size_t xbase = 0;
    if (upd) {
        xbase = (size_t)b8 * TSEQ * 4096 + colbase + c16;
        xp0 = xproj[xbase];          xp1 = xproj[xbase + 1024];
        xp2 = xproj[xbase + 2048];   xp3 = xproj[xbase + 3072];
    }

    // poll ownership: 64B = rows pr,pr+1 of j-region pj
    const int pj = tid >> 2, pr = (tid & 3) * 2;
    const int sw = (pj & 7) << 3;
    int widx[4];
#pragma unroll
    for (int k = 0; k < 4; ++k)
        widx[k] = pj * 256 + ((pr * 16 + k * 8) ^ sw);

    // MFMA A-fragment swizzled read offsets
    int aro[4];
#pragma unroll
    for (int i = 0; i < 4; ++i) {
        int swr = ((2 * i + (ksl >> 1)) & 7) << 3;
        aro[i] = (ksl >> 1) * 256 + ((lrow * 16 + (ksl & 1) * 8) ^ swr);
    }

    for (int t = 0; t < TSEQ; ++t) {
        // ---- bulk poll hseq[t] -> hstage[t&1] ----
        const u32* src = (const u32*)hseq + (size_t)t * 4096 + pj * 64 + pr * 8;
        u32x4 P0, P1, P2, P3;
        for (;;) {
            asm volatile("global_load_dwordx4 %0, %1, off sc0 sc1" : "=v"(P0) : "v"(src));
            asm volatile("global_load_dwordx4 %0, %1, off sc0 sc1" : "=v"(P1) : "v"(src + 4));
            asm volatile("global_load_dwordx4 %0, %1, off sc0 sc1" : "=v"(P2) : "v"(src + 8));
            asm volatile("global_load_dwordx4 %0, %1, off sc0 sc1" : "=v"(P3) : "v"(src + 12));
            asm volatile("s_waitcnt vmcnt(0)" ::: "memory");
            __builtin_amdgcn_sched_barrier(0);
            u32 a = min4u(P0), b = min4u(P1), c = min4u(P2), d = min4u(P3);
            u32 mn = (a < b ? a : b); u32 mn2 = (c < d ? c : d);
            if ((mn < mn2 ? mn : mn2) != 0u) break;
        }
        {
            u16* hb2 = &hstage[t & 1][0];
            *(u32x4*)(hb2 + widx[0]) = P0;
            *(u32x4*)(hb2 + widx[1]) = P1;
            *(u32x4*)(hb2 + widx[2]) = P2;
            *(u32x4*)(hb2 + widx[3]) = P3;
        }
        __syncthreads();   // staging ready; separates update(t-1) S-reads from S-writes

        // ---- MFMA from LDS staging (swizzled reads) ----
        const u16* sb = &hstage[t & 1][0];
        f32x4 ac0 = {}, ac1 = {}, ac2 = {}, ac3 = {};
#pragma unroll
        for (int g = 0; g < 8; ++g) {
            bf16x8 a0 = *(const bf16x8*)(sb + g * 2048 + 0 * 512 + aro[0]);
            bf16x8 a1 = *(const bf16x8*)(sb + g * 2048 + 1 * 512 + aro[1]);
            bf16x8 a2 = *(const bf16x8*)(sb + g * 2048 + 2 * 512 + aro[2]);
            bf16x8 a3 = *(const bf16x8*)(sb + g * 2048 + 3 * 512 + aro[3]);
            ac0 = __builtin_amdgcn_mfma_f32_16x16x32_bf16(a0, Bf[g * 4 + 0], ac0, 0, 0, 0);
            ac1 = __builtin_amdgcn_mfma_f32_16x16x32_bf16(a1, Bf[g * 4 + 1], ac1, 0, 0, 0);
            ac2 = __builtin_amdgcn_mfma_f32_16x16x32_bf16(a2, Bf[g * 4 + 2], ac2, 0, 0, 0);
            ac3 = __builtin_amdgcn_mfma_f32_16x16x32_bf16(a3, Bf[g * 4 + 3], ac3, 0, 0, 0);
        }
        if (ksl < 2) {
#pragma unroll
            for (int r = 0; r < 4; ++r)
                S[wq][ksl * 4 + r][lrow] = ac0[r] + ac1[r] + ac2[r] + ac3[r];
        }
        __syncthreads();

        // ---- update & h publication (no drain, no flag) ----
        if (upd) {
            float gi = S[0][b8][c16] + xp0;
            float gf = S[1][b8][c16] + xp1;
            float gg = S[2][b8][c16] + xp2;
            float go = S[3][b8][c16] + xp3;
            float iv = sigm(gi), fv = sigm(gf), ov = sigm(go);
            float gv = tanhf(gg);
            creg = fv * creg + iv * gv;
            float hv = ov * tanhf(creg);
            u16 hbx = f2bf(hv) | 1;                 // LSB tag: stored word != 0
            int w0 = (int)hbx;
            int w1 = __shfl_down(w0, 1);
            if (!(c16 & 1)) {
                u32 wp = (u32)(u16)w0 | ((u32)(u16)w1 << 16);
                u32* dst = (u32*)hseq + (size_t)(t + 1) * 4096 + bid * 64 + b8 * 8 + (c16 >> 1);
                __hip_atomic_store(dst, wp, __ATOMIC_RELAXED, __HIP_MEMORY_SCOPE_AGENT);
                u32* hd = (u32*)hall
                          + ((((size_t)b8 * TSEQ + t) * KDIM + colbase + c16) >> 1);
                *hd = wp;
            }
            if (t == TSEQ - 1) {
                outTail[b8 * KDIM + colbase + c16] = hv;
                outTail[8192 + b8 * KDIM + colbase + c16] = creg;
            }
            int tn = (t + 1 < TSEQ) ? t + 1 : t;
            size_t xb = xbase + (size_t)tn * 4096;
            xp0 = xproj[xb];        xp1 = xproj[xb + 1024];
            xp2 = xproj[xb + 2048]; xp3 = xproj[xb + 3072];
        }
    }
}

// ---------------- fused lse merge + in-place backward expansion ----------------

__global__ __launch_bounds__(256)
void merge_final(const float* __restrict__ pmax, const float* __restrict__ psum,
                 float* __restrict__ out)
{
    const int m = blockIdx.x;
    const int tid = threadIdx.x;
    __shared__ float smx[4], ssm[4], slse;

    float mx = -3.0e38f, s = 0.f;
    for (int i = tid; i < NT; i += 256) {
        float pm = pmax[(size_t)m * NT + i];
        float ps = psum[(size_t)m * NT + i];
        if (pm > mx) { s *= __expf(mx - pm); mx = pm; }
        s += ps * __expf(pm - mx);
    }
#pragma unroll
    for (int off = 32; off > 0; off >>= 1) {
        float om = __shfl_xor(mx, off), os = __shfl_xor(s, off);
        float nm = fmaxf(mx, om);
        s = s * __expf(mx - nm) + os * __expf(om - nm);
        mx = nm;
    }
    if ((tid & 63) == 0) { smx[tid >> 6] = mx; ssm[tid >> 6] = s; }
    __syncthreads();
    if (tid == 0) {
        float M = fmaxf(fmaxf(smx[0], smx[1]), fmaxf(smx[2], smx[3]));
        float S4 = ssm[0] * __expf(smx[0] - M) + ssm[1] * __expf(smx[1] - M) +
                   ssm[2] * __expf(smx[2] - M) + ssm[3] * __expf(smx[3] - M);
        slse = M + __logf(S4);
    }
    __syncthreads();
    const float L = slse;

    // expand bf16 logits (front half of f32 row slot) -> f32 minus lse,
    // BACKWARD in chunks so reads precede clobbering writes.
    const u32* srcw = (const u32*)out + (size_t)m * VOCAB;
    float* dst = out + (size_t)m * VOCAB;
    const int NCH = (VOCAB + 2047) / 2048;                   // 25
    for (int c = NCH - 1; c >= 0; --c) {
        int e0 = c * 2048 + tid * 8;
        int w0i = e0 >> 1;
        u32 w0 = srcw[w0i], w1 = srcw[w0i + 1], w2 = srcw[w0i + 2], w3 = srcw[w0i + 3];
        __syncthreads();
        float f[8];
        f[0] = __builtin_bit_cast(float, (w0 & 0xFFFFu) << 16) - L;
        f[1] = __builtin_bit_cast(float, w0 & 0xFFFF0000u) - L;
        f[2] = __builtin_bit_cast(float, (w1 & 0xFFFFu) << 16) - L;
        f[3] = __builtin_bit_cast(float, w1 & 0xFFFF0000u) - L;
        f[4] = __builtin_bit_cast(float, (w2 & 0xFFFFu) << 16) - L;
        f[5] = __builtin_bit_cast(float, w2 & 0xFFFF0000u) - L;
        f[6] = __builtin_bit_cast(float, (w3 & 0xFFFFu) << 16) - L;
        f[7] = __builtin_bit_cast(float, w3 & 0xFFFF0000u) - L;
        if (e0 + 8 <= VOCAB) {
#pragma unroll
            for (int k = 0; k < 8; ++k) dst[e0 + k] = f[k];
        } else {
#pragma unroll
            for (int k = 0; k < 8; ++k) if (e0 + k < VOCAB) dst[e0 + k] = f[k];
        }
    }
}

// ---------------- host ----------------

extern "C" void kernel_launch(void* const* d_in, const int* in_sizes, int n_in,
                              void* d_out, int out_size, void* d_ws, size_t ws_size,
                              hipStream_t stream)
{
    const int*   x    = (const int*)d_in[0];
    const float* embW = (const float*)d_in[1];
    const float* Wih  = (const float*)d_in[2];
    const float* Whh  = (const float*)d_in[3];
    const float* bih  = (const float*)d_in[4];
    const float* bhh  = (const float*)d_in[5];
    const float* decb = (const float*)d_in[6];
    float* out = (float*)d_out;

    char* p = (char*)d_ws;
    auto carve = [&](size_t bytes) {
        char* q = p;
        p += (bytes + 255) & ~(size_t)255;
        return q;
    };
    u16*   embW_bf = (u16*)carve((size_t)VOCAB * KDIM * 2);    // 98.2 MB
    u16*   Wih_bf  = (u16*)carve((size_t)4096 * KDIM * 2);     // 8 MB
    u16*   Whh_bf  = (u16*)carve((size_t)4096 * KDIM * 2);     // 8 MB
    u16*   emb_bf  = (u16*)carve((size_t)MROWS * KDIM * 2);    // 4 MB
    float* xproj   = (float*)carve((size_t)MROWS * 4096 * 4);  // 33.6 MB
    u16*   hall_bf = (u16*)carve((size_t)MROWS * KDIM * 2);    // 4 MB
    u16*   hseq    = (u16*)carve((size_t)(TSEQ + 1) * 4096 * 4); // 4.2 MB
    float* pmax    = (float*)carve((size_t)MROWS * NT * 4);    // 6.4 MB
    float* psum    = (float*)carve((size_t)MROWS * NT * 4);    // 6.4 MB
    float* bsum    = (float*)carve((size_t)4096 * 4);

    // consolidated prep (convs for Wih/Whh + gather + hseq init + bias)
    prep_all<<<PREP_BLOCKS, 256, 0, stream>>>((const float4*)Wih, (ushort4*)Wih_bf,
                                              (const float4*)Whh, (ushort4*)Whh_bf,
                                              x, embW, (ushort4*)emb_bf,
                                              (u32*)hseq, bih, bhh, bsum);

    // x_proj = emb * W_ih^T + (b_ih + b_hh), with embW conversion overlapped
    {
        dim3 g(MROWS / BM, GBY + HBY);
        gemm_bt_conv<<<g, 256, 0, stream>>>(emb_bf, Wih_bf, bsum, xproj,
                                            4096, 4096, KDIM, 4096,
                                            (const float4*)embW, (ushort4*)embW_bf);
    }

    // LSTM recurrence (pure 64-block persistent kernel)
    lstm_persist<<<NBLK, 256, 0, stream>>>(Whh_bf, xproj, hseq, hall_bf, out + LOGN);

    // logits (bf16, packed) = h_all * embW^T + dec_b, with fused max/sumexp
    {
        dim3 g(MROWS / BM, NTILE);
        gemm_dec<<<g, 256, 0, stream>>>(hall_bf, embW_bf, decb, (u16*)out, pmax, psum);
    }

    // fused lse merge + in-place expansion
    merge_final<<<MROWS, 256, 0, stream>>>(pmax, psum, out);
}

// Round 15
// 1195.610 us; speedup vs baseline: 1.0978x; 1.0978x over previous
//
#include <hip/hip_runtime.h>

typedef float f32x4 __attribute__((ext_vector_type(4)));
typedef __bf16 bf16x8 __attribute__((ext_vector_type(8)));
typedef unsigned int u32x4 __attribute__((ext_vector_type(4)));
typedef unsigned short u16;
typedef unsigned int u32;

#define VOCAB 50257
#define KDIM 1024
#define MROWS 2048
#define TSEQ 256
#define NBLK 64
#define NHELP 96
#define NTILE 393            // ceil(VOCAB/128)
#define NT (NTILE * 2)       // partial slots per row (2 waves/col-tile)
#define LOGN ((size_t)MROWS * VOCAB)

__device__ __forceinline__ u16 f2bf(float f) {
    u32 u = __builtin_bit_cast(u32, f);
    u = (u + 0x7FFFu + ((u >> 16) & 1u)) >> 16;
    return (u16)u;
}

__device__ __forceinline__ float sigm(float x) { return 1.0f / (1.0f + __expf(-x)); }

__device__ __forceinline__ u32 min4u(u32x4 v) {
    u32 a = v.x < v.y ? v.x : v.y;
    u32 b = v.z < v.w ? v.z : v.w;
    return a < b ? a : b;
}

__device__ __forceinline__ ushort4 cvt4(float4 v) {
    ushort4 o;
    o.x = f2bf(v.x); o.y = f2bf(v.y); o.z = f2bf(v.z); o.w = f2bf(v.w);
    return o;
}

// ---------------- consolidated prep: one launch (no embW conv here) ----------------
// [0,4096)       conv Wih
// [4096,8192)    conv Whh
// [8192,10240)   gather_emb
// [10240,14352)  init_hseq
// [14352,14368)  bias_sum

#define PB_GATH 8192
#define PB_HSEQ 10240
#define PB_BIAS 14352
#define PREP_BLOCKS 14368

__global__ __launch_bounds__(256)
void prep_all(const float4* __restrict__ Wih, ushort4* __restrict__ Wih_bf,
              const float4* __restrict__ Whh, ushort4* __restrict__ Whh_bf,
              const int* __restrict__ x, const float* __restrict__ embW,
              ushort4* __restrict__ emb_bf, u32* __restrict__ hseq,
              const float* __restrict__ bih, const float* __restrict__ bhh,
              float* __restrict__ bsum)
{
    const int bid = blockIdx.x, tid = threadIdx.x;
    if (bid < 4096) {
        long i = (long)bid * 256 + tid;
        Wih_bf[i] = cvt4(Wih[i]);
    } else if (bid < PB_GATH) {
        long i = (long)(bid - 4096) * 256 + tid;
        Whh_bf[i] = cvt4(Whh[i]);
    } else if (bid < PB_HSEQ) {
        int m = bid - PB_GATH;
        int row = x[m];
        float4 v = ((const float4*)(embW + (size_t)row * KDIM))[tid];
        emb_bf[(size_t)m * 256 + tid] = cvt4(v);
    } else if (bid < PB_BIAS) {
        int i = (bid - PB_HSEQ) * 256 + tid;   // < 257*4096
        hseq[i] = (i < 4096) ? 0x00010001u : 0u;
    } else {
        int i = (bid - PB_BIAS) * 256 + tid;
        if (i < 4096) bsum[i] = bih[i] + bhh[i];
    }
}

// ---------------- bf16 MFMA GEMM (C = A * B^T + bias), BK=64, swizzled LDS ----------------

#define BM 128
#define BN 128
#define BK 64

__device__ __forceinline__ void gl_lds16(const u16* g, const u16* l) {
    __builtin_amdgcn_global_load_lds(
        (const __attribute__((address_space(1))) u32*)g,
        (__attribute__((address_space(3))) u32*)l, 16, 0, 0);
}

__global__ __launch_bounds__(256, 2)
void gemm_bt(const u16* __restrict__ A, const u16* __restrict__ Bm,
             const float* __restrict__ bias, float* __restrict__ C,
             int N, int Nb, int K, int ldc)
{
    __shared__ __align__(16) u16 As[BM * BK];
    __shared__ __align__(16) u16 Bs[BN * BK];
    const int tid  = threadIdx.x;
    const int lane = tid & 63;
    const int wid  = tid >> 6;

    const int gx  = gridDim.x;
    const int nwg = gx * gridDim.y;
    const int lin = blockIdx.y * gx + blockIdx.x;
    const int qq = nwg >> 3, rr = nwg & 7;
    const int xcd = lin & 7, idx = lin >> 3;
    const int neu = (xcd < rr) ? (xcd * (qq + 1) + idx)
                               : (rr * (qq + 1) + (xcd - rr) * qq + idx);
    const int bm = neu % gx;
    const int bn = neu / gx;

    const int wr = wid >> 1, wc = wid & 1;

    const u16* gA[4]; const u16* gB[4];
    const u16* ldsA[4]; const u16* ldsB[4];
#pragma unroll
    for (int r = 0; r < 4; ++r) {
        int L = r * 256 + tid;
        int row = L >> 3, ps = L & 7;
        int ls = ps ^ (row & 7);
        gA[r] = A + (size_t)(bm * BM + row) * K + ls * 8;
        int brow = bn * BN + row; brow = brow < Nb ? brow : Nb - 1;
        gB[r] = Bm + (size_t)brow * K + ls * 8;
        ldsA[r] = As + (r * 256 + wid * 64) * 8;
        ldsB[r] = Bs + (r * 256 + wid * 64) * 8;
    }

    const int lrow = lane & 15, ksl = lane >> 4;
    int aoff[4][2], boff[4][2];
#pragma unroll
    for (int i = 0; i < 4; ++i)
#pragma unroll
        for (int ks = 0; ks < 2; ++ks) {
            int ar = wr * 64 + i * 16 + lrow;
            aoff[i][ks] = ar * BK + (((ks * 4 + ksl) ^ (ar & 7)) * 8);
            int br = wc * 64 + i * 16 + lrow;
            boff[i][ks] = br * BK + (((ks * 4 + ksl) ^ (br & 7)) * 8);
        }

    f32x4 acc[4][4] = {};
    for (int kt = 0; kt < K; kt += BK) {
#pragma unroll
        for (int r = 0; r < 4; ++r) gl_lds16(gA[r] + kt, ldsA[r]);
#pragma unroll
        for (int r = 0; r < 4; ++r) gl_lds16(gB[r] + kt, ldsB[r]);
        __syncthreads();
        bf16x8 af[4][2], bfb[4][2];
#pragma unroll
        for (int i = 0; i < 4; ++i)
#pragma unroll
            for (int ks = 0; ks < 2; ++ks) {
                af[i][ks]  = *(const bf16x8*)(As + aoff[i][ks]);
                bfb[i][ks] = *(const bf16x8*)(Bs + boff[i][ks]);
            }
#pragma unroll
        for (int ks = 0; ks < 2; ++ks)
#pragma unroll
            for (int mi = 0; mi < 4; ++mi)
#pragma unroll
                for (int ni = 0; ni < 4; ++ni)
                    acc[mi][ni] = __builtin_amdgcn_mfma_f32_16x16x32_bf16(
                        af[mi][ks], bfb[ni][ks], acc[mi][ni], 0, 0, 0);
        __syncthreads();
    }

    const int crl = lane >> 4, ccl = lane & 15;
    const int row0 = bm * BM + wr * 64, col0 = bn * BN + wc * 64;
#pragma unroll
    for (int ni = 0; ni < 4; ++ni) {
        int col = col0 + ni * 16 + ccl;
        if (col < N) {
            float bv = bias[col];
#pragma unroll
            for (int mi = 0; mi < 4; ++mi) {
                int row = row0 + mi * 16 + crl * 4;
                float* cp = C + (size_t)row * ldc + col;
#pragma unroll
                for (int r = 0; r < 4; ++r)
                    cp[(size_t)r * ldc] = acc[mi][ni][r] + bv;
            }
        }
    }
}

// ---- decoder GEMM: bf16 C (packed into f32 row slots) + fused max/sumexp ----

__global__ __launch_bounds__(256, 3)
void gemm_dec(const u16* __restrict__ A, const u16* __restrict__ Bm,
              const float* __restrict__ bias, u16* __restrict__ Cb,
              float* __restrict__ pmax, float* __restrict__ psum)
{
    const int N = VOCAB, Nb = VOCAB, K = KDIM;
    __shared__ __align__(16) u16 As[BM * BK];
    __shared__ __align__(16) u16 Bs[BN * BK];
    const int tid  = threadIdx.x;
    const int lane = tid & 63;
    const int wid  = tid >> 6;

    const int gx  = gridDim.x;
    const int nwg = gx * gridDim.y;
    const int lin = blockIdx.y * gx + blockIdx.x;
    const int qq = nwg >> 3, rr = nwg & 7;
    const int xcd = lin & 7, idx = lin >> 3;
    const int neu = (xcd < rr) ? (xcd * (qq + 1) + idx)
                               : (rr * (qq + 1) + (xcd - rr) * qq + idx);
    const int bm = neu % gx;
    const int bn = neu / gx;

    const int wr = wid >> 1, wc = wid & 1;

    const u16* gA[4]; const u16* gB[4];
    const u16* ldsA[4]; const u16* ldsB[4];
#pragma unroll
    for (int r = 0; r < 4; ++r) {
        int L = r * 256 + tid;
        int row = L >> 3, ps = L & 7;
        int ls = ps ^ (row & 7);
        gA[r] = A + (size_t)(bm * BM + row) * K + ls * 8;
        int brow = bn * BN + row; brow = brow < Nb ? brow : Nb - 1;
        gB[r] = Bm + (size_t)brow * K + ls * 8;
        ldsA[r] = As + (r * 256 + wid * 64) * 8;
        ldsB[r] = Bs + (r * 256 + wid * 64) * 8;
    }

    const int lrow = lane & 15, ksl = lane >> 4;
    int aoff[4][2], boff[4][2];
#pragma unroll
    for (int i = 0; i < 4; ++i)
#pragma unroll
        for (int ks = 0; ks < 2; ++ks) {
            int ar = wr * 64 + i * 16 + lrow;
            aoff[i][ks] = ar * BK + (((ks * 4 + ksl) ^ (ar & 7)) * 8);
            int br = wc * 64 + i * 16 + lrow;
            boff[i][ks] = br * BK + (((ks * 4 + ksl) ^ (br & 7)) * 8);
        }

    f32x4 acc[4][4] = {};
    for (int kt = 0; kt < K; kt += BK) {
#pragma unroll
        for (int r = 0; r < 4; ++r) gl_lds16(gA[r] + kt, ldsA[r]);
#pragma unroll
        for (int r = 0; r < 4; ++r) gl_lds16(gB[r] + kt, ldsB[r]);
        __syncthreads();
        bf16x8 af[4][2], bfb[4][2];
#pragma unroll
        for (int i = 0; i < 4; ++i)
#pragma unroll
            for (int ks = 0; ks < 2; ++ks) {
                af[i][ks]  = *(const bf16x8*)(As + aoff[i][ks]);
                bfb[i][ks] = *(const bf16x8*)(Bs + boff[i][ks]);
            }
#pragma unroll
        for (int ks = 0; ks < 2; ++ks)
#pragma unroll
            for (int mi = 0; mi < 4; ++mi)
#pragma unroll
                for (int ni = 0; ni < 4; ++ni)
                    acc[mi][ni] = __builtin_amdgcn_mfma_f32_16x16x32_bf16(
                        af[mi][ks], bfb[ni][ks], acc[mi][ni], 0, 0, 0);
        __syncthreads();
    }

    const int crl = lane >> 4, ccl = lane & 15;
    const int row0 = bm * BM + wr * 64, col0 = bn * BN + wc * 64;
    float bve[4]; bool vld[4];
#pragma unroll
    for (int ni = 0; ni < 4; ++ni) {
        int col = col0 + ni * 16 + ccl;
        vld[ni] = col < N;
        bve[ni] = vld[ni] ? bias[col] : 0.f;
    }
    // bf16 logits packed at the front of each f32 row slot: row stride VOCAB*2 u16
#pragma unroll
    for (int ni = 0; ni < 4; ++ni) {
        if (vld[ni]) {
            int col = col0 + ni * 16 + ccl;
#pragma unroll
            for (int mi = 0; mi < 4; ++mi) {
                int row = row0 + mi * 16 + crl * 4;
                u16* cp = Cb + (size_t)row * (VOCAB * 2) + col;
#pragma unroll
                for (int r = 0; r < 4; ++r)
                    cp[(size_t)r * (VOCAB * 2)] = f2bf(acc[mi][ni][r] + bve[ni]);
            }
        }
    }
    // fused partial log-softmax reduction
#pragma unroll
    for (int mi = 0; mi < 4; ++mi)
#pragma unroll
        for (int r = 0; r < 4; ++r) {
            int row = row0 + mi * 16 + crl * 4 + r;
            float v0 = vld[0] ? acc[mi][0][r] + bve[0] : -3.0e38f;
            float v1 = vld[1] ? acc[mi][1][r] + bve[1] : -3.0e38f;
            float v2 = vld[2] ? acc[mi][2][r] + bve[2] : -3.0e38f;
            float v3 = vld[3] ? acc[mi][3][r] + bve[3] : -3.0e38f;
            float rmax = fmaxf(fmaxf(v0, v1), fmaxf(v2, v3));
#pragma unroll
            for (int m2 = 1; m2 < 16; m2 <<= 1) rmax = fmaxf(rmax, __shfl_xor(rmax, m2));
            float rs = __expf(v0 - rmax) + __expf(v1 - rmax) +
                       __expf(v2 - rmax) + __expf(v3 - rmax);
#pragma unroll
            for (int m2 = 1; m2 < 16; m2 <<= 1) rs += __shfl_xor(rs, m2);
            if (ccl == 0) {
                pmax[(size_t)row * NT + bn * 2 + wc] = rmax;
                psum[(size_t)row * NT + bn * 2 + wc] = rs;
            }
        }
}

// ---------------- persistent LSTM + 96 throttled embW-conv helpers ----------------
// Blocks 0..63: recurrence (data-as-tag bulk poll, XOR-swizzled LDS staging).
// Blocks 64..159: grid-stride embW f32->bf16 conversion (halved vs r12 to cut
// contention on the latency-critical recurrence; finishes well within its window).

__global__ __launch_bounds__(256, 1)
void lstm_persist(const u16* __restrict__ Whh,     // [4096][1024] bf16
                  const float* __restrict__ xproj, // [2048][4096] f32
                  u16* __restrict__ hseq,          // [257][64][8][16] bf16
                  u16* __restrict__ hall,          // [2048][1024] bf16
                  float* __restrict__ outTail,     // h[8][1024], c[8][1024] f32
                  const float4* __restrict__ embW, // helpers: f32 source
                  ushort4* __restrict__ embW_bf)   // helpers: bf16 dest
{
    const int tid = threadIdx.x;
    const int bid = blockIdx.x;

    if (bid >= NBLK) {                          // ---- helper: embW conversion ----
        long i = (long)(bid - NBLK) * 256 + tid;
        const long n4 = (long)VOCAB * KDIM / 4;
        const long stride = (long)NHELP * 256;
        for (; i < n4; i += stride) embW_bf[i] = cvt4(embW[i]);
        return;
    }

    const int lane = tid & 63;
    const int wq   = tid >> 6;                 // gate quadrant (i,f,g,o)
    const int lrow = lane & 15, ksl = lane >> 4;
    const int colbase = bid * 16;

    // persistent Whh fragments, pinned via volatile asm
    bf16x8 Bf[32];
    {
        const u16* bp = Whh + (size_t)(wq * 1024 + colbase + lrow) * KDIM + ksl * 8;
#pragma unroll
        for (int kk = 0; kk < 32; ++kk)
            asm volatile("global_load_dwordx4 %0, %1, off"
                         : "=v"(Bf[kk]) : "v"(bp + kk * 32));
        asm volatile("s_waitcnt vmcnt(0)" ::: "memory");
        __builtin_amdgcn_sched_barrier(0);
    }

    __shared__ float S[4][8][16];
    __shared__ __align__(16) u16 hstage[2][16384];   // 64 KB, XOR-swizzled

    // zero pad region (rows 8..15 of each j-region), once
    for (int i = tid; i < 2 * 64 * 8; i += 256) {
        int buf = i >> 9, rem = i & 511;
        int j = rem >> 3, rowoff = rem & 7;
        u32x4 z = {0, 0, 0, 0};
        *(u32x4*)(&hstage[buf][j * 256 + 128 + rowoff * 16]) = z;
        *(u32x4*)(&hstage[buf][j * 256 + 128 + rowoff * 16 + 8]) = z;
    }

    const bool upd = tid < 128;
    const int b8 = tid >> 4, c16 = tid & 15;
    float creg = 0.f;
    float xp0 = 0.f, xp1 = 0.f, xp2 = 0.f, xp3 = 0.f;
    size_t xbase = 0;
    if (upd) {
        xbase = (size_t)b8 * TSEQ * 4096 + colbase + c16;
        xp0 = xproj[xbase];          xp1 = xproj[xbase + 1024];
        xp2 = xproj[xbase + 2048];   xp3 = xproj[xbase + 3072];
    }

    // poll ownership: 64B = rows pr,pr+1 of j-region pj
    const int pj = tid >> 2, pr = (tid & 3) * 2;
    const int sw = (pj & 7) << 3;
    int widx[4];
#pragma unroll
    for (int k = 0; k < 4; ++k)
        widx[k] = pj * 256 + ((pr * 16 + k * 8) ^ sw);

    // MFMA A-fragment swizzled read offsets
    int aro[4];
#pragma unroll
    for (int i = 0; i < 4; ++i) {
        int swr = ((2 * i + (ksl >> 1)) & 7) << 3;
        aro[i] = (ksl >> 1) * 256 + ((lrow * 16 + (ksl & 1) * 8) ^ swr);
    }

    for (int t = 0; t < TSEQ; ++t) {
        // ---- bulk poll hseq[t] -> hstage[t&1] ----
        const u32* src = (const u32*)hseq + (size_t)t * 4096 + pj * 64 + pr * 8;
        u32x4 P0, P1, P2, P3;
        for (;;) {
            asm volatile("global_load_dwordx4 %0, %1, off sc0 sc1" : "=v"(P0) : "v"(src));
            asm volatile("global_load_dwordx4 %0, %1, off sc0 sc1" : "=v"(P1) : "v"(src + 4));
            asm volatile("global_load_dwordx4 %0, %1, off sc0 sc1" : "=v"(P2) : "v"(src + 8));
            asm volatile("global_load_dwordx4 %0, %1, off sc0 sc1" : "=v"(P3) : "v"(src + 12));
            asm volatile("s_waitcnt vmcnt(0)" ::: "memory");
            __builtin_amdgcn_sched_barrier(0);
            u32 a = min4u(P0), b = min4u(P1), c = min4u(P2), d = min4u(P3);
            u32 mn = (a < b ? a : b); u32 mn2 = (c < d ? c : d);
            if ((mn < mn2 ? mn : mn2) != 0u) break;
        }
        {
            u16* hb2 = &hstage[t & 1][0];
            *(u32x4*)(hb2 + widx[0]) = P0;
            *(u32x4*)(hb2 + widx[1]) = P1;
            *(u32x4*)(hb2 + widx[2]) = P2;
            *(u32x4*)(hb2 + widx[3]) = P3;
        }
        __syncthreads();   // staging ready; separates update(t-1) S-reads from S-writes

        // ---- MFMA from LDS staging (swizzled reads) ----
        const u16* sb = &hstage[t & 1][0];
        f32x4 ac0 = {}, ac1 = {}, ac2 = {}, ac3 = {};
#pragma unroll
        for (int g = 0; g < 8; ++g) {
            bf16x8 a0 = *(const bf16x8*)(sb + g * 2048 + 0 * 512 + aro[0]);
            bf16x8 a1 = *(const bf16x8*)(sb + g * 2048 + 1 * 512 + aro[1]);
            bf16x8 a2 = *(const bf16x8*)(sb + g * 2048 + 2 * 512 + aro[2]);
            bf16x8 a3 = *(const bf16x8*)(sb + g * 2048 + 3 * 512 + aro[3]);
            ac0 = __builtin_amdgcn_mfma_f32_16x16x32_bf16(a0, Bf[g * 4 + 0], ac0, 0, 0, 0);
            ac1 = __builtin_amdgcn_mfma_f32_16x16x32_bf16(a1, Bf[g * 4 + 1], ac1, 0, 0, 0);
            ac2 = __builtin_amdgcn_mfma_f32_16x16x32_bf16(a2, Bf[g * 4 + 2], ac2, 0, 0, 0);
            ac3 = __builtin_amdgcn_mfma_f32_16x16x32_bf16(a3, Bf[g * 4 + 3], ac3, 0, 0, 0);
        }
        if (ksl < 2) {
#pragma unroll
            for (int r = 0; r < 4; ++r)
                S[wq][ksl * 4 + r][lrow] = ac0[r] + ac1[r] + ac2[r] + ac3[r];
        }
        __syncthreads();

        // ---- update & h publication (no drain, no flag) ----
        if (upd) {
            float gi = S[0][b8][c16] + xp0;
            float gf = S[1][b8][c16] + xp1;
            float gg = S[2][b8][c16] + xp2;
            float go = S[3][b8][c16] + xp3;
            float iv = sigm(gi), fv = sigm(gf), ov = sigm(go);
            float gv = tanhf(gg);
            creg = fv * creg + iv * gv;
            float hv = ov * tanhf(creg);
            u16 hbx = f2bf(hv) | 1;                 // LSB tag: stored word != 0
            int w0 = (int)hbx;
            int w1 = __shfl_down(w0, 1);
            if (!(c16 & 1)) {
                u32 wp = (u32)(u16)w0 | ((u32)(u16)w1 << 16);
                u32* dst = (u32*)hseq + (size_t)(t + 1) * 4096 + bid * 64 + b8 * 8 + (c16 >> 1);
                __hip_atomic_store(dst, wp, __ATOMIC_RELAXED, __HIP_MEMORY_SCOPE_AGENT);
                u32* hd = (u32*)hall
                          + ((((size_t)b8 * TSEQ + t) * KDIM + colbase + c16) >> 1);
                *hd = wp;
            }
            if (t == TSEQ - 1) {
                outTail[b8 * KDIM + colbase + c16] = hv;
                outTail[8192 + b8 * KDIM + colbase + c16] = creg;
            }
            int tn = (t + 1 < TSEQ) ? t + 1 : t;
            size_t xb = xbase + (size_t)tn * 4096;
            xp0 = xproj[xb];        xp1 = xproj[xb + 1024];
            xp2 = xproj[xb + 2048]; xp3 = xproj[xb + 3072];
        }
    }
}

// ---------------- fused lse merge + in-place backward expansion ----------------

__global__ __launch_bounds__(256)
void merge_final(const float* __restrict__ pmax, const float* __restrict__ psum,
                 float* __restrict__ out)
{
    const int m = blockIdx.x;
    const int tid = threadIdx.x;
    __shared__ float smx[4], ssm[4], slse;

    float mx = -3.0e38f, s = 0.f;
    for (int i = tid; i < NT; i += 256) {
        float pm = pmax[(size_t)m * NT + i];
        float ps = psum[(size_t)m * NT + i];
        if (pm > mx) { s *= __expf(mx - pm); mx = pm; }
        s += ps * __expf(pm - mx);
    }
#pragma unroll
    for (int off = 32; off > 0; off >>= 1) {
        float om = __shfl_xor(mx, off), os = __shfl_xor(s, off);
        float nm = fmaxf(mx, om);
        s = s * __expf(mx - nm) + os * __expf(om - nm);
        mx = nm;
    }
    if ((tid & 63) == 0) { smx[tid >> 6] = mx; ssm[tid >> 6] = s; }
    __syncthreads();
    if (tid == 0) {
        float M = fmaxf(fmaxf(smx[0], smx[1]), fmaxf(smx[2], smx[3]));
        float S4 = ssm[0] * __expf(smx[0] - M) + ssm[1] * __expf(smx[1] - M) +
                   ssm[2] * __expf(smx[2] - M) + ssm[3] * __expf(smx[3] - M);
        slse = M + __logf(S4);
    }
    __syncthreads();
    const float L = slse;

    // expand bf16 logits (front half of f32 row slot) -> f32 minus lse,
    // BACKWARD in chunks so reads precede clobbering writes.
    const u32* srcw = (const u32*)out + (size_t)m * VOCAB;
    float* dst = out + (size_t)m * VOCAB;
    const int NCH = (VOCAB + 2047) / 2048;                   // 25
    for (int c = NCH - 1; c >= 0; --c) {
        int e0 = c * 2048 + tid * 8;
        int w0i = e0 >> 1;
        u32 w0 = srcw[w0i], w1 = srcw[w0i + 1], w2 = srcw[w0i + 2], w3 = srcw[w0i + 3];
        __syncthreads();
        float f[8];
        f[0] = __builtin_bit_cast(float, (w0 & 0xFFFFu) << 16) - L;
        f[1] = __builtin_bit_cast(float, w0 & 0xFFFF0000u) - L;
        f[2] = __builtin_bit_cast(float, (w1 & 0xFFFFu) << 16) - L;
        f[3] = __builtin_bit_cast(float, w1 & 0xFFFF0000u) - L;
        f[4] = __builtin_bit_cast(float, (w2 & 0xFFFFu) << 16) - L;
        f[5] = __builtin_bit_cast(float, w2 & 0xFFFF0000u) - L;
        f[6] = __builtin_bit_cast(float, (w3 & 0xFFFFu) << 16) - L;
        f[7] = __builtin_bit_cast(float, w3 & 0xFFFF0000u) - L;
        if (e0 + 8 <= VOCAB) {
#pragma unroll
            for (int k = 0; k < 8; ++k) dst[e0 + k] = f[k];
        } else {
#pragma unroll
            for (int k = 0; k < 8; ++k) if (e0 + k < VOCAB) dst[e0 + k] = f[k];
        }
    }
}

// ---------------- host ----------------

extern "C" void kernel_launch(void* const* d_in, const int* in_sizes, int n_in,
                              void* d_out, int out_size, void* d_ws, size_t ws_size,
                              hipStream_t stream)
{
    const int*   x    = (const int*)d_in[0];
    const float* embW = (const float*)d_in[1];
    const float* Wih  = (const float*)d_in[2];
    const float* Whh  = (const float*)d_in[3];
    const float* bih  = (const float*)d_in[4];
    const float* bhh  = (const float*)d_in[5];
    const float* decb = (const float*)d_in[6];
    float* out = (float*)d_out;

    char* p = (char*)d_ws;
    auto carve = [&](size_t bytes) {
        char* q = p;
        p += (bytes + 255) & ~(size_t)255;
        return q;
    };
    u16*   embW_bf = (u16*)carve((size_t)VOCAB * KDIM * 2);    // 98.2 MB
    u16*   Wih_bf  = (u16*)carve((size_t)4096 * KDIM * 2);     // 8 MB
    u16*   Whh_bf  = (u16*)carve((size_t)4096 * KDIM * 2);     // 8 MB
    u16*   emb_bf  = (u16*)carve((size_t)MROWS * KDIM * 2);    // 4 MB
    float* xproj   = (float*)carve((size_t)MROWS * 4096 * 4);  // 33.6 MB
    u16*   hall_bf = (u16*)carve((size_t)MROWS * KDIM * 2);    // 4 MB
    u16*   hseq    = (u16*)carve((size_t)(TSEQ + 1) * 4096 * 4); // 4.2 MB
    float* pmax    = (float*)carve((size_t)MROWS * NT * 4);    // 6.4 MB
    float* psum    = (float*)carve((size_t)MROWS * NT * 4);    // 6.4 MB
    float* bsum    = (float*)carve((size_t)4096 * 4);

    // consolidated prep (convs for Wih/Whh + gather + hseq init + bias)
    prep_all<<<PREP_BLOCKS, 256, 0, stream>>>((const float4*)Wih, (ushort4*)Wih_bf,
                                              (const float4*)Whh, (ushort4*)Whh_bf,
                                              x, embW, (ushort4*)emb_bf,
                                              (u32*)hseq, bih, bhh, bsum);

    // x_proj = emb * W_ih^T + (b_ih + b_hh)
    {
        dim3 g(MROWS / BM, 4096 / BN);
        gemm_bt<<<g, 256, 0, stream>>>(emb_bf, Wih_bf, bsum, xproj, 4096, 4096, KDIM, 4096);
    }

    // LSTM recurrence (blocks 0..63) + 96 embW conversion helpers (64..159)
    lstm_persist<<<NBLK + NHELP, 256, 0, stream>>>(Whh_bf, xproj, hseq, hall_bf,
                                                   out + LOGN,
                                                   (const float4*)embW,
                                                   (ushort4*)embW_bf);

    // logits (bf16, packed) = h_all * embW^T + dec_b, with fused max/sumexp
    {
        dim3 g(MROWS / BM, NTILE);
        gemm_dec<<<g, 256, 0, stream>>>(hall_bf, embW_bf, decb, (u16*)out, pmax, psum);
    }

    // fused lse merge + in-place expansion
    merge_final<<<MROWS, 256, 0, stream>>>(pmax, psum, out);
}